// Round 8
// baseline (253.081 us; speedup 1.0000x reference)
//
#include <hip/hip_runtime.h>
#include <cstdint>
#include <cstddef>

#define SL 4096
#define DM 768

typedef short s16x8 __attribute__((ext_vector_type(8)));
typedef unsigned short u16x8 __attribute__((ext_vector_type(8)));
typedef unsigned short u16x4 __attribute__((ext_vector_type(4)));
typedef float f32x4 __attribute__((ext_vector_type(4)));
typedef float f32x16 __attribute__((ext_vector_type(16)));
typedef unsigned int u32x4 __attribute__((ext_vector_type(4)));

__device__ __forceinline__ unsigned short f2bf(float f) {
  unsigned u = __float_as_uint(f);
  u = u + 0x7fffu + ((u >> 16) & 1u);   // round-to-nearest-even
  return (unsigned short)(u >> 16);
}

// 16B-block XOR swizzle within a 64-short (128B) row (guide G4/T2) — GEMM kernels.
__device__ __forceinline__ int swz(int row, int col) {
  return (row << 6) + ((((col >> 3) ^ row) & 7) << 3) + (col & 7);
}

#define ASYNC16(G, L)                                                        \
  __builtin_amdgcn_global_load_lds(                                          \
      (const __attribute__((address_space(1))) void*)(G),                    \
      (__attribute__((address_space(3))) void*)(L), 16, 0, 0)

#define WAITB()                                   \
  do {                                            \
    asm volatile("s_waitcnt vmcnt(0)" ::: "memory"); \
    __builtin_amdgcn_s_barrier();                 \
  } while (0)

// ---- fused prep: x->bf16 cvt, W_attn^T, W_out^T, kmx zero ----
__device__ __forceinline__ void tr_body(
    const float* __restrict__ in, unsigned short* __restrict__ out,
    int R, int C, int bx, int by, float (*tile)[65], int t) {
  const int r0 = by * 64, c0 = bx * 64;
  const int lr = t >> 2, lcb = (t & 3) * 16;
  #pragma unroll
  for (int j = 0; j < 16; j += 4) {
    f32x4 v = *reinterpret_cast<const f32x4*>(in + (size_t)(r0 + lr) * C + c0 + lcb + j);
    tile[lr][lcb + j + 0] = v[0];
    tile[lr][lcb + j + 1] = v[1];
    tile[lr][lcb + j + 2] = v[2];
    tile[lr][lcb + j + 3] = v[3];
  }
  __syncthreads();
  #pragma unroll
  for (int j = 0; j < 16; j += 4) {
    u16x4 o;
    o[0] = f2bf(tile[lcb + j + 0][lr]);
    o[1] = f2bf(tile[lcb + j + 1][lr]);
    o[2] = f2bf(tile[lcb + j + 2][lr]);
    o[3] = f2bf(tile[lcb + j + 3][lr]);
    *reinterpret_cast<u16x4*>(out + (size_t)(c0 + lr) * R + r0 + lcb + j) = o;
  }
}

extern "C" __global__ __launch_bounds__(256) void k_prep(
    const float* __restrict__ x, const float* __restrict__ Wa,
    const float* __restrict__ Wo, unsigned short* __restrict__ xbf,
    unsigned short* __restrict__ wat, unsigned short* __restrict__ wot,
    unsigned* __restrict__ kmx) {
  __shared__ float tile[64][65];
  const int b = blockIdx.x, t = threadIdx.x;
  if (b < 3072) {
    if (b == 0 && t < 12) kmx[t] = 0u;
    const int i = (b * 256 + t) * 4;
    f32x4 v = *reinterpret_cast<const f32x4*>(x + i);
    u16x4 o;
    o[0] = f2bf(v[0]); o[1] = f2bf(v[1]); o[2] = f2bf(v[2]); o[3] = f2bf(v[3]);
    *reinterpret_cast<u16x4*>(xbf + i) = o;
  } else if (b < 3504) {
    const int bb = b - 3072;
    tr_body(Wa, wat, 768, 2304, bb % 36, bb / 36, tile, t);
  } else {
    const int bb = b - 3504;
    tr_body(Wo, wot, 768, 768, bb % 12, bb / 12, tile, t);
  }
}

// ---- QKV GEMM, 128x128 tile, BK=64, async dbuf; epilogue computes row norms ----
extern "C" __global__ __launch_bounds__(256) void k_qkv(
    const unsigned short* __restrict__ xbf, const unsigned short* __restrict__ wt,
    const float* __restrict__ bias, unsigned short* __restrict__ qb,
    unsigned short* __restrict__ kbo, unsigned short* __restrict__ vtb,
    float* __restrict__ qn2, unsigned* __restrict__ kmx) {
  __shared__ alignas(16) unsigned short a_lds[2][8192];
  __shared__ alignas(16) unsigned short b_lds[2][8192];
  const int t = threadIdx.x, w = t >> 6, l = t & 63;
  const int l15 = l & 15, lg = l >> 4;
  const int wr = w >> 1, wc = w & 1;
  const int n0 = blockIdx.x * 128, m0 = blockIdx.y * 128;
  f32x4 acc[4][4];
  #pragma unroll
  for (int mt = 0; mt < 4; mt++)
    #pragma unroll
    for (int nt = 0; nt < 4; nt++) acc[mt][nt] = (f32x4)0.f;
  int soff[4];
  #pragma unroll
  for (int c = 0; c < 4; c++) {
    int i = c * 256 + t;
    int row = i >> 3, bp = i & 7;
    soff[c] = row * DM + (bp ^ (row & 7)) * 8;
  }
  const unsigned short* asrc = xbf + (size_t)m0 * DM;
  const unsigned short* bsrc = wt + (size_t)n0 * DM;

#define STAGE128(B, KK)                                                   \
  do {                                                                    \
    _Pragma("unroll")                                                     \
    for (int c = 0; c < 4; c++) {                                         \
      ASYNC16(asrc + (KK) + soff[c], &a_lds[B][0] + c * 2048 + w * 512);  \
      ASYNC16(bsrc + (KK) + soff[c], &b_lds[B][0] + c * 2048 + w * 512);  \
    }                                                                     \
  } while (0)

#define GEMM128(B)                                                            \
  do {                                                                        \
    _Pragma("unroll")                                                         \
    for (int kc = 0; kc < 2; kc++) {                                          \
      s16x8 af[4], bfv[4];                                                    \
      _Pragma("unroll")                                                       \
      for (int mt = 0; mt < 4; mt++)                                          \
        af[mt] = *reinterpret_cast<const s16x8*>(                             \
            &a_lds[B][swz(wr * 64 + mt * 16 + l15, kc * 32 + lg * 8)]);       \
      _Pragma("unroll")                                                       \
      for (int nt = 0; nt < 4; nt++)                                          \
        bfv[nt] = *reinterpret_cast<const s16x8*>(                            \
            &b_lds[B][swz(wc * 64 + nt * 16 + l15, kc * 32 + lg * 8)]);       \
      _Pragma("unroll")                                                       \
      for (int mt = 0; mt < 4; mt++)                                          \
        _Pragma("unroll")                                                     \
        for (int nt = 0; nt < 4; nt++)                                        \
          acc[mt][nt] = __builtin_amdgcn_mfma_f32_16x16x32_bf16(              \
              af[mt], bfv[nt], acc[mt][nt], 0, 0, 0);                         \
    }                                                                         \
  } while (0)

  STAGE128(0, 0);
  WAITB();
  #pragma unroll 1
  for (int kk = 0; kk < DM; kk += 128) {
    STAGE128(1, kk + 64);
    GEMM128(0);
    WAITB();
    if (kk + 128 < DM) STAGE128(0, kk + 128);
    GEMM128(1);
    WAITB();
  }
#undef STAGE128
#undef GEMM128

  const int secn = (n0 >= 1536) ? 2 : (n0 >= 768 ? 1 : 0);
  const int nbase = n0 - secn * 768 + wc * 64;   // 64-aligned within section
  const int h = nbase >> 6;                      // this wave's head
  const int mrow0 = m0 + wr * 64;
  float bv4[4];
  #pragma unroll
  for (int nt = 0; nt < 4; nt++) bv4[nt] = bias[secn * 768 + nbase + nt * 16 + l15];

  if (secn == 0) {
    const float QS = 0.180336880f;               // 0.125*log2(e)
    float s2[4][4];
    #pragma unroll
    for (int mt = 0; mt < 4; mt++) {
      #pragma unroll
      for (int r = 0; r < 4; r++) s2[mt][r] = 0.f;
    }
    #pragma unroll
    for (int mt = 0; mt < 4; mt++) {
      #pragma unroll
      for (int nt = 0; nt < 4; nt++) {
        const int d = nt * 16 + l15;
        #pragma unroll
        for (int r = 0; r < 4; r++) {
          const int m = mrow0 + mt * 16 + lg * 4 + r;
          float v = (acc[mt][nt][r] + bv4[nt]) * QS;
          qb[((size_t)h * SL + m) * 64 + d] = f2bf(v);
          s2[mt][r] = fmaf(v, v, s2[mt][r]);
        }
      }
    }
    #pragma unroll
    for (int mt = 0; mt < 4; mt++)
      #pragma unroll
      for (int r = 0; r < 4; r++) {
        #pragma unroll
        for (int off = 1; off < 16; off <<= 1)
          s2[mt][r] += __shfl_xor(s2[mt][r], off, 64);
      }
    if (l15 == 0) {
      #pragma unroll
      for (int mt = 0; mt < 4; mt++)
        #pragma unroll
        for (int r = 0; r < 4; r++)
          qn2[(size_t)h * SL + mrow0 + mt * 16 + lg * 4 + r] = s2[mt][r];
    }
  } else if (secn == 1) {
    float s2[4][4];
    #pragma unroll
    for (int mt = 0; mt < 4; mt++) {
      #pragma unroll
      for (int r = 0; r < 4; r++) s2[mt][r] = 0.f;
    }
    #pragma unroll
    for (int mt = 0; mt < 4; mt++) {
      #pragma unroll
      for (int nt = 0; nt < 4; nt++) {
        const int d = nt * 16 + l15;
        #pragma unroll
        for (int r = 0; r < 4; r++) {
          const int m = mrow0 + mt * 16 + lg * 4 + r;
          float v = acc[mt][nt][r] + bv4[nt];
          kbo[((size_t)h * SL + m) * 64 + d] = f2bf(v);
          s2[mt][r] = fmaf(v, v, s2[mt][r]);
        }
      }
    }
    float rm = 0.f;
    #pragma unroll
    for (int mt = 0; mt < 4; mt++)
      #pragma unroll
      for (int r = 0; r < 4; r++) {
        #pragma unroll
        for (int off = 1; off < 16; off <<= 1)
          s2[mt][r] += __shfl_xor(s2[mt][r], off, 64);
        rm = fmaxf(rm, s2[mt][r]);
      }
    rm = fmaxf(rm, __shfl_xor(rm, 16, 64));
    rm = fmaxf(rm, __shfl_xor(rm, 32, 64));
    if (l == 0) atomicMax(kmx + h, __float_as_uint(rm));   // norm^2, >=0
  } else {
    #pragma unroll
    for (int mt = 0; mt < 4; mt++) {
      #pragma unroll
      for (int nt = 0; nt < 4; nt++) {
        const int d = nt * 16 + l15;
        u16x4 o;
        #pragma unroll
        for (int r = 0; r < 4; r++) o[r] = f2bf(acc[mt][nt][r] + bv4[nt]);
        *reinterpret_cast<u16x4*>(
            vtb + ((size_t)h * 64 + d) * SL + mrow0 + mt * 16 + lg * 4) = o;
      }
    }
  }
}

// ---- Flash attention, LDS-FREE inner loop: K and V fragments read directly
// global->VGPR (swapped-operand layouts are row-per-lane, so a b128 load IS the
// fragment). No staging, no in-loop barriers, no vmcnt(0) drains. 4 waves =
// 2 q-subtiles x 2 KV-halves; KVBLK=64; fixed-bound softmax (-M via MFMA);
// row-sum via MFMA ones-trick. LDS only for the final half-merge.
extern "C" __global__ __launch_bounds__(256) void k_attn(
    const unsigned short* __restrict__ qb, const unsigned short* __restrict__ kbi,
    const unsigned short* __restrict__ vt, const float* __restrict__ qn2,
    const unsigned* __restrict__ kmx, unsigned short* __restrict__ aout) {
  __shared__ float o_m[2][32][68];
  __shared__ float l_m[2][32];
  const int t = threadIdx.x, w = t >> 6, l = t & 63;
  const int l31 = l & 31, s = l >> 5;
  const int half = w >> 1, qs = w & 1;
  // XCD swizzle: each XCD gets 96 consecutive head-major ids (<=2 heads' KV in L2)
  const int bid = blockIdx.x;
  const int sid = (bid & 7) * 96 + (bid >> 3);
  const int h = sid >> 6, qt = sid & 63;
  const unsigned short* qh = qb + (size_t)h * SL * 64;
  const unsigned short* kh = kbi + ((size_t)h * SL + half * 2048) * 64;
  const unsigned short* vh = vt + (size_t)h * 64 * SL + half * 2048;
  const int q = qt * 64 + qs * 32 + l31;
  const float M = sqrtf(qn2[(size_t)h * SL + q] * __uint_as_float(kmx[h]));
  s16x8 qf[4];
  #pragma unroll
  for (int c = 0; c < 4; c++)
    qf[c] = *reinterpret_cast<const s16x8*>(qh + (size_t)q * 64 + c * 16 + s * 8);
  s16x8 ones;
  #pragma unroll
  for (int e = 0; e < 8; e++) ones[e] = (short)0x3F80;     // bf16 1.0
  s16x8 qm = (s16x8)0;
  if (s == 0) qm[0] = (short)f2bf(-M);                      // k-slot 0 holds -M(q)
  f32x16 ot0 = (f32x16)0.f, ot1 = (f32x16)0.f, lacc = (f32x16)0.f;
  const int klane = l31 * 64 + s * 8;                       // K row/lane offset
  const int vlane = l31 * SL + s * 8;                       // V^T row/lane offset

  #pragma unroll 1
  for (int lb = 0; lb < 2048; lb += 64) {
    // K fragments: lane = key row (kt*32+l31), 16B along d
    const unsigned short* kp = kh + (size_t)lb * 64 + klane;
    s16x8 kf[2][4];
    #pragma unroll
    for (int kt = 0; kt < 2; kt++)
      #pragma unroll
      for (int c = 0; c < 4; c++)
        kf[kt][c] = *reinterpret_cast<const s16x8*>(kp + kt * 2048 + c * 16);
    f32x16 st0 = (f32x16)0.f, st1 = (f32x16)0.f;
    __builtin_amdgcn_s_setprio(1);
    #pragma unroll
    for (int c = 0; c < 4; c++) {
      st0 = __builtin_amdgcn_mfma_f32_32x32x16_bf16(kf[0][c], qf[c], st0, 0, 0, 0);
      st1 = __builtin_amdgcn_mfma_f32_32x32x16_bf16(kf[1][c], qf[c], st1, 0, 0, 0);
    }
    st0 = __builtin_amdgcn_mfma_f32_32x32x16_bf16(ones, qm, st0, 0, 0, 0);
    st1 = __builtin_amdgcn_mfma_f32_32x32x16_bf16(ones, qm, st1, 0, 0, 0);
    __builtin_amdgcn_s_setprio(0);
    // V fragments: lane = d row (dt*32+l31), 16B along seq; latency hides under exp2
    const unsigned short* vp = vh + lb + vlane;
    s16x8 vf[2][4];
    #pragma unroll
    for (int dt = 0; dt < 2; dt++)
      #pragma unroll
      for (int cc = 0; cc < 4; cc++)
        vf[dt][cc] = *reinterpret_cast<const s16x8*>(vp + dt * 32 * SL + cc * 16);
    #pragma unroll
    for (int r = 0; r < 16; r++) st0[r] = exp2f(st0[r]);
    #pragma unroll
    for (int r = 0; r < 16; r++) st1[r] = exp2f(st1[r]);
    // P pack + PV per 16-key chunk
    #pragma unroll
    for (int cc = 0; cc < 4; cc++) {
      const int m0 = (cc & 1) * 8;
      const f32x16& stk = (cc < 2) ? st0 : st1;
      unsigned w0, w1, w2, w3;
      asm("v_cvt_pk_bf16_f32 %0, %1, %2" : "=v"(w0) : "v"(stk[m0 + 0]), "v"(stk[m0 + 1]));
      asm("v_cvt_pk_bf16_f32 %0, %1, %2" : "=v"(w1) : "v"(stk[m0 + 2]), "v"(stk[m0 + 3]));
      asm("v_cvt_pk_bf16_f32 %0, %1, %2" : "=v"(w2) : "v"(stk[m0 + 4]), "v"(stk[m0 + 5]));
      asm("v_cvt_pk_bf16_f32 %0, %1, %2" : "=v"(w3) : "v"(stk[m0 + 6]), "v"(stk[m0 + 7]));
      asm volatile("v_permlane32_swap_b32 %0, %1" : "+v"(w0), "+v"(w2));
      asm volatile("v_permlane32_swap_b32 %0, %1" : "+v"(w1), "+v"(w3));
      u32x4 wv_;
      wv_[0] = w0; wv_[1] = w1; wv_[2] = w2; wv_[3] = w3;
      s16x8 pbf = *reinterpret_cast<s16x8*>(&wv_);
      __builtin_amdgcn_s_setprio(1);
      ot0 = __builtin_amdgcn_mfma_f32_32x32x16_bf16(vf[0][cc], pbf, ot0, 0, 0, 0);
      ot1 = __builtin_amdgcn_mfma_f32_32x32x16_bf16(vf[1][cc], pbf, ot1, 0, 0, 0);
      lacc = __builtin_amdgcn_mfma_f32_32x32x16_bf16(ones, pbf, lacc, 0, 0, 0);
      __builtin_amdgcn_s_setprio(0);
    }
  }
  // merge the two halves (same M shift => plain adds)
  const float lsum = lacc[0];
  if (half == 1) {
    #pragma unroll
    for (int dt = 0; dt < 2; dt++) {
      #pragma unroll
      for (int rq = 0; rq < 4; rq++) {
        f32x4 v;
        #pragma unroll
        for (int j = 0; j < 4; j++) v[j] = (dt ? ot1 : ot0)[rq * 4 + j];
        *reinterpret_cast<f32x4*>(&o_m[qs][l31][dt * 32 + rq * 8 + s * 4]) = v;
      }
    }
    if (s == 0) l_m[qs][l31] = lsum;
  }
  __syncthreads();
  if (half == 0) {
    const float linv = 1.f / (lsum + l_m[qs][l31]);
    #pragma unroll
    for (int dt = 0; dt < 2; dt++) {
      #pragma unroll
      for (int rq = 0; rq < 4; rq++) {
        f32x4 vb_ = *reinterpret_cast<const f32x4*>(&o_m[qs][l31][dt * 32 + rq * 8 + s * 4]);
        u16x4 o;
        #pragma unroll
        for (int j = 0; j < 4; j++)
          o[j] = f2bf(((dt ? ot1 : ot0)[rq * 4 + j] + vb_[j]) * linv);
        *reinterpret_cast<u16x4*>(aout + (size_t)q * DM + h * 64 + dt * 32 + rq * 8 + s * 4) = o;
      }
    }
  }
}

// ---- out-proj GEMM + bias + residual -> y (fp32), 128x128 tile, async dbuf ----
extern "C" __global__ __launch_bounds__(256) void k_out(
    const unsigned short* __restrict__ abf, const unsigned short* __restrict__ wot,
    const float* __restrict__ bias, const float* __restrict__ x, float* __restrict__ y) {
  __shared__ alignas(16) unsigned short a_lds[2][8192];
  __shared__ alignas(16) unsigned short b_lds[2][8192];
  const int t = threadIdx.x, w = t >> 6, l = t & 63;
  const int l15 = l & 15, lg = l >> 4;
  const int wr = w >> 1, wc = w & 1;
  const int n0 = blockIdx.x * 128, m0 = blockIdx.y * 128;
  f32x4 acc[4][4];
  #pragma unroll
  for (int mt = 0; mt < 4; mt++)
    #pragma unroll
    for (int nt = 0; nt < 4; nt++) acc[mt][nt] = (f32x4)0.f;
  int soff[4];
  #pragma unroll
  for (int c = 0; c < 4; c++) {
    int i = c * 256 + t;
    int row = i >> 3, bp = i & 7;
    soff[c] = row * DM + (bp ^ (row & 7)) * 8;
  }
  const unsigned short* asrc = abf + (size_t)m0 * DM;
  const unsigned short* bsrc = wot + (size_t)n0 * DM;

#define STAGE128(B, KK)                                                   \
  do {                                                                    \
    _Pragma("unroll")                                                     \
    for (int c = 0; c < 4; c++) {                                         \
      ASYNC16(asrc + (KK) + soff[c], &a_lds[B][0] + c * 2048 + w * 512);  \
      ASYNC16(bsrc + (KK) + soff[c], &b_lds[B][0] + c * 2048 + w * 512);  \
    }                                                                     \
  } while (0)

#define GEMM128(B)                                                            \
  do {                                                                        \
    _Pragma("unroll")                                                         \
    for (int kc = 0; kc < 2; kc++) {                                          \
      s16x8 af[4], bfv[4];                                                    \
      _Pragma("unroll")                                                       \
      for (int mt = 0; mt < 4; mt++)                                          \
        af[mt] = *reinterpret_cast<const s16x8*>(                             \
            &a_lds[B][swz(wr * 64 + mt * 16 + l15, kc * 32 + lg * 8)]);       \
      _Pragma("unroll")                                                       \
      for (int nt = 0; nt < 4; nt++)                                          \
        bfv[nt] = *reinterpret_cast<const s16x8*>(                            \
            &b_lds[B][swz(wc * 64 + nt * 16 + l15, kc * 32 + lg * 8)]);       \
      _Pragma("unroll")                                                       \
      for (int mt = 0; mt < 4; mt++)                                          \
        _Pragma("unroll")                                                     \
        for (int nt = 0; nt < 4; nt++)                                        \
          acc[mt][nt] = __builtin_amdgcn_mfma_f32_16x16x32_bf16(              \
              af[mt], bfv[nt], acc[mt][nt], 0, 0, 0);                         \
    }                                                                         \
  } while (0)

  STAGE128(0, 0);
  WAITB();
  #pragma unroll 1
  for (int kk = 0; kk < DM; kk += 128) {
    STAGE128(1, kk + 64);
    GEMM128(0);
    WAITB();
    if (kk + 128 < DM) STAGE128(0, kk + 128);
    GEMM128(1);
    WAITB();
  }
#undef STAGE128
#undef GEMM128

  const int mrow0 = m0 + wr * 64;
  #pragma unroll
  for (int nt = 0; nt < 4; nt++) {
    const int n = n0 + wc * 64 + nt * 16 + l15;
    const float bv = bias[n];
    #pragma unroll
    for (int mt = 0; mt < 4; mt++) {
      #pragma unroll
      for (int r = 0; r < 4; r++) {
        const int m = mrow0 + mt * 16 + lg * 4 + r;
        y[(size_t)m * DM + n] = acc[mt][nt][r] + bv + x[(size_t)m * DM + n];
      }
    }
  }
}

extern "C" __global__ __launch_bounds__(256) void k_ln(
    const float* __restrict__ y, const float* __restrict__ g, const float* __restrict__ b,
    float* __restrict__ out) {
  const int row = blockIdx.x, t = threadIdx.x;
  const float* yr = y + (size_t)row * DM;
  float v0 = yr[t], v1 = yr[t + 256], v2 = yr[t + 512];
  float sum = v0 + v1 + v2;
  float sq = v0 * v0 + v1 * v1 + v2 * v2;
  #pragma unroll
  for (int off = 1; off < 64; off <<= 1) {
    sum += __shfl_xor(sum, off, 64);
    sq += __shfl_xor(sq, off, 64);
  }
  __shared__ float ls[8];
  const int wv = t >> 6, l = t & 63;
  if (l == 0) { ls[wv] = sum; ls[4 + wv] = sq; }
  __syncthreads();
  sum = ls[0] + ls[1] + ls[2] + ls[3];
  sq = ls[4] + ls[5] + ls[6] + ls[7];
  const float mu = sum * (1.f / DM);
  const float rstd = rsqrtf(sq * (1.f / DM) - mu * mu + 1e-5f);
  out[(size_t)row * DM + t] = (v0 - mu) * rstd * g[t] + b[t];
  out[(size_t)row * DM + t + 256] = (v1 - mu) * rstd * g[t + 256] + b[t + 256];
  out[(size_t)row * DM + t + 512] = (v2 - mu) * rstd * g[t + 512] + b[t + 512];
}

extern "C" void kernel_launch(void* const* d_in, const int* in_sizes, int n_in,
                              void* d_out, int out_size, void* d_ws, size_t ws_size,
                              hipStream_t stream) {
  (void)in_sizes; (void)n_in; (void)out_size; (void)ws_size;
  const float* x = (const float*)d_in[0];
  const float* Wa = (const float*)d_in[1];
  const float* ba = (const float*)d_in[2];
  const float* Wo = (const float*)d_in[3];
  const float* bo = (const float*)d_in[4];
  const float* lng = (const float*)d_in[5];
  const float* lnb = (const float*)d_in[6];
  float* out = (float*)d_out;

  unsigned short* ws16 = (unsigned short*)d_ws;
  unsigned short* xbf = ws16;                 // 4096x768
  unsigned short* wat = xbf + 3145728;        // 2304x768 (W_attn^T)
  unsigned short* wot = wat + 1769472;        // 768x768  (W_out^T)
  unsigned short* qbf = wot + 589824;         // [12][4096][64]
  unsigned short* kbf = qbf + 3145728;        // [12][4096][64]
  unsigned short* vtb = kbf + 3145728;        // [12][64][4096]
  unsigned short* aob = vtb + 3145728;        // 4096x768 attn out
  float* ybuf = (float*)(aob + 3145728);      // 4096x768 fp32
  float* qn2 = ybuf + 3145728;                // [12][4096] |q|^2
  unsigned* kmx = (unsigned*)(qn2 + 49152);   // [12] max |k|^2 (as uint)

  k_prep<<<3648, 256, 0, stream>>>(x, Wa, Wo, xbf, wat, wot, kmx);
  k_qkv<<<dim3(18, 32), 256, 0, stream>>>(xbf, wat, ba, qbf, kbf, vtb, qn2, kmx);
  k_attn<<<768, 256, 0, stream>>>(qbf, kbf, vtb, qn2, kmx, aob);
  k_out<<<dim3(6, 32), 256, 0, stream>>>(aob, wot, bo, x, ybuf);
  k_ln<<<4096, 256, 0, stream>>>(ybuf, lng, lnb, out);
}

// Round 9
// 220.465 us; speedup vs baseline: 1.1479x; 1.1479x over previous
//
#include <hip/hip_runtime.h>
#include <cstdint>
#include <cstddef>

#define SL 4096
#define DM 768

typedef short s16x8 __attribute__((ext_vector_type(8)));
typedef unsigned short u16x8 __attribute__((ext_vector_type(8)));
typedef unsigned short u16x4 __attribute__((ext_vector_type(4)));
typedef float f32x4 __attribute__((ext_vector_type(4)));
typedef float f32x16 __attribute__((ext_vector_type(16)));
typedef unsigned int u32x4 __attribute__((ext_vector_type(4)));

__device__ __forceinline__ unsigned short f2bf(float f) {
  unsigned u = __float_as_uint(f);
  u = u + 0x7fffu + ((u >> 16) & 1u);   // round-to-nearest-even
  return (unsigned short)(u >> 16);
}

// 16B-block XOR swizzle within a 64-short (128B) row (guide G4/T2).
__device__ __forceinline__ int swz(int row, int col) {
  return (row << 6) + ((((col >> 3) ^ row) & 7) << 3) + (col & 7);
}

// attention tile swizzle: rows of 64 shorts, full 8-slot XOR (0 conflicts, R4)
__device__ __forceinline__ int aswz(int row, int col) {
  return (row << 6) + ((((col >> 3) ^ row ^ (row >> 3)) & 7) << 3) + (col & 7);
}

#define ASYNC16(G, L)                                                        \
  __builtin_amdgcn_global_load_lds(                                          \
      (const __attribute__((address_space(1))) void*)(G),                    \
      (__attribute__((address_space(3))) void*)(L), 16, 0, 0)

#define WAITB()                                   \
  do {                                            \
    asm volatile("s_waitcnt vmcnt(0)" ::: "memory"); \
    __builtin_amdgcn_s_barrier();                 \
  } while (0)

#define MF32(A, B, C) __builtin_amdgcn_mfma_f32_32x32x16_bf16((A), (B), (C), 0, 0, 0)

// ---- fused prep: x->bf16 cvt, W_attn^T, W_out^T, kmx zero ----
__device__ __forceinline__ void tr_body(
    const float* __restrict__ in, unsigned short* __restrict__ out,
    int R, int C, int bx, int by, float (*tile)[65], int t) {
  const int r0 = by * 64, c0 = bx * 64;
  const int lr = t >> 2, lcb = (t & 3) * 16;
  #pragma unroll
  for (int j = 0; j < 16; j += 4) {
    f32x4 v = *reinterpret_cast<const f32x4*>(in + (size_t)(r0 + lr) * C + c0 + lcb + j);
    tile[lr][lcb + j + 0] = v[0];
    tile[lr][lcb + j + 1] = v[1];
    tile[lr][lcb + j + 2] = v[2];
    tile[lr][lcb + j + 3] = v[3];
  }
  __syncthreads();
  #pragma unroll
  for (int j = 0; j < 16; j += 4) {
    u16x4 o;
    o[0] = f2bf(tile[lcb + j + 0][lr]);
    o[1] = f2bf(tile[lcb + j + 1][lr]);
    o[2] = f2bf(tile[lcb + j + 2][lr]);
    o[3] = f2bf(tile[lcb + j + 3][lr]);
    *reinterpret_cast<u16x4*>(out + (size_t)(c0 + lr) * R + r0 + lcb + j) = o;
  }
}

extern "C" __global__ __launch_bounds__(256) void k_prep(
    const float* __restrict__ x, const float* __restrict__ Wa,
    const float* __restrict__ Wo, unsigned short* __restrict__ xbf,
    unsigned short* __restrict__ wat, unsigned short* __restrict__ wot,
    unsigned* __restrict__ kmx) {
  __shared__ float tile[64][65];
  const int b = blockIdx.x, t = threadIdx.x;
  if (b < 3072) {
    if (b == 0 && t < 12) kmx[t] = 0u;
    const int i = (b * 256 + t) * 4;
    f32x4 v = *reinterpret_cast<const f32x4*>(x + i);
    u16x4 o;
    o[0] = f2bf(v[0]); o[1] = f2bf(v[1]); o[2] = f2bf(v[2]); o[3] = f2bf(v[3]);
    *reinterpret_cast<u16x4*>(xbf + i) = o;
  } else if (b < 3504) {
    const int bb = b - 3072;
    tr_body(Wa, wat, 768, 2304, bb % 36, bb / 36, tile, t);
  } else {
    const int bb = b - 3504;
    tr_body(Wo, wot, 768, 768, bb % 12, bb / 12, tile, t);
  }
}

// ---- QKV GEMM, 128x128 tile, BK=64, async dbuf; epilogue computes row norms ----
extern "C" __global__ __launch_bounds__(256) void k_qkv(
    const unsigned short* __restrict__ xbf, const unsigned short* __restrict__ wt,
    const float* __restrict__ bias, unsigned short* __restrict__ qb,
    unsigned short* __restrict__ kbo, unsigned short* __restrict__ vtb,
    float* __restrict__ qn2, unsigned* __restrict__ kmx) {
  __shared__ alignas(16) unsigned short a_lds[2][8192];
  __shared__ alignas(16) unsigned short b_lds[2][8192];
  const int t = threadIdx.x, w = t >> 6, l = t & 63;
  const int l15 = l & 15, lg = l >> 4;
  const int wr = w >> 1, wc = w & 1;
  const int n0 = blockIdx.x * 128, m0 = blockIdx.y * 128;
  f32x4 acc[4][4];
  #pragma unroll
  for (int mt = 0; mt < 4; mt++)
    #pragma unroll
    for (int nt = 0; nt < 4; nt++) acc[mt][nt] = (f32x4)0.f;
  int soff[4];
  #pragma unroll
  for (int c = 0; c < 4; c++) {
    int i = c * 256 + t;
    int row = i >> 3, bp = i & 7;
    soff[c] = row * DM + (bp ^ (row & 7)) * 8;
  }
  const unsigned short* asrc = xbf + (size_t)m0 * DM;
  const unsigned short* bsrc = wt + (size_t)n0 * DM;

#define STAGE128(B, KK)                                                   \
  do {                                                                    \
    _Pragma("unroll")                                                     \
    for (int c = 0; c < 4; c++) {                                         \
      ASYNC16(asrc + (KK) + soff[c], &a_lds[B][0] + c * 2048 + w * 512);  \
      ASYNC16(bsrc + (KK) + soff[c], &b_lds[B][0] + c * 2048 + w * 512);  \
    }                                                                     \
  } while (0)

#define GEMM128(B)                                                            \
  do {                                                                        \
    _Pragma("unroll")                                                         \
    for (int kc = 0; kc < 2; kc++) {                                          \
      s16x8 af[4], bfv[4];                                                    \
      _Pragma("unroll")                                                       \
      for (int mt = 0; mt < 4; mt++)                                          \
        af[mt] = *reinterpret_cast<const s16x8*>(                             \
            &a_lds[B][swz(wr * 64 + mt * 16 + l15, kc * 32 + lg * 8)]);       \
      _Pragma("unroll")                                                       \
      for (int nt = 0; nt < 4; nt++)                                          \
        bfv[nt] = *reinterpret_cast<const s16x8*>(                            \
            &b_lds[B][swz(wc * 64 + nt * 16 + l15, kc * 32 + lg * 8)]);       \
      _Pragma("unroll")                                                       \
      for (int mt = 0; mt < 4; mt++)                                          \
        _Pragma("unroll")                                                     \
        for (int nt = 0; nt < 4; nt++)                                        \
          acc[mt][nt] = __builtin_amdgcn_mfma_f32_16x16x32_bf16(              \
              af[mt], bfv[nt], acc[mt][nt], 0, 0, 0);                         \
    }                                                                         \
  } while (0)

  STAGE128(0, 0);
  WAITB();
  #pragma unroll 1
  for (int kk = 0; kk < DM; kk += 128) {
    STAGE128(1, kk + 64);
    GEMM128(0);
    WAITB();
    if (kk + 128 < DM) STAGE128(0, kk + 128);
    GEMM128(1);
    WAITB();
  }
#undef STAGE128
#undef GEMM128

  const int secn = (n0 >= 1536) ? 2 : (n0 >= 768 ? 1 : 0);
  const int nbase = n0 - secn * 768 + wc * 64;   // 64-aligned within section
  const int h = nbase >> 6;                      // this wave's head
  const int mrow0 = m0 + wr * 64;
  float bv4[4];
  #pragma unroll
  for (int nt = 0; nt < 4; nt++) bv4[nt] = bias[secn * 768 + nbase + nt * 16 + l15];

  if (secn == 0) {
    const float QS = 0.180336880f;               // 0.125*log2(e)
    float s2[4][4];
    #pragma unroll
    for (int mt = 0; mt < 4; mt++) {
      #pragma unroll
      for (int r = 0; r < 4; r++) s2[mt][r] = 0.f;
    }
    #pragma unroll
    for (int mt = 0; mt < 4; mt++) {
      #pragma unroll
      for (int nt = 0; nt < 4; nt++) {
        const int d = nt * 16 + l15;
        #pragma unroll
        for (int r = 0; r < 4; r++) {
          const int m = mrow0 + mt * 16 + lg * 4 + r;
          float v = (acc[mt][nt][r] + bv4[nt]) * QS;
          qb[((size_t)h * SL + m) * 64 + d] = f2bf(v);
          s2[mt][r] = fmaf(v, v, s2[mt][r]);
        }
      }
    }
    #pragma unroll
    for (int mt = 0; mt < 4; mt++)
      #pragma unroll
      for (int r = 0; r < 4; r++) {
        #pragma unroll
        for (int off = 1; off < 16; off <<= 1)
          s2[mt][r] += __shfl_xor(s2[mt][r], off, 64);
      }
    if (l15 == 0) {
      #pragma unroll
      for (int mt = 0; mt < 4; mt++)
        #pragma unroll
        for (int r = 0; r < 4; r++)
          qn2[(size_t)h * SL + mrow0 + mt * 16 + lg * 4 + r] = s2[mt][r];
    }
  } else if (secn == 1) {
    float s2[4][4];
    #pragma unroll
    for (int mt = 0; mt < 4; mt++) {
      #pragma unroll
      for (int r = 0; r < 4; r++) s2[mt][r] = 0.f;
    }
    #pragma unroll
    for (int mt = 0; mt < 4; mt++) {
      #pragma unroll
      for (int nt = 0; nt < 4; nt++) {
        const int d = nt * 16 + l15;
        #pragma unroll
        for (int r = 0; r < 4; r++) {
          const int m = mrow0 + mt * 16 + lg * 4 + r;
          float v = acc[mt][nt][r] + bv4[nt];
          kbo[((size_t)h * SL + m) * 64 + d] = f2bf(v);
          s2[mt][r] = fmaf(v, v, s2[mt][r]);
        }
      }
    }
    float rm = 0.f;
    #pragma unroll
    for (int mt = 0; mt < 4; mt++)
      #pragma unroll
      for (int r = 0; r < 4; r++) {
        #pragma unroll
        for (int off = 1; off < 16; off <<= 1)
          s2[mt][r] += __shfl_xor(s2[mt][r], off, 64);
        rm = fmaxf(rm, s2[mt][r]);
      }
    rm = fmaxf(rm, __shfl_xor(rm, 16, 64));
    rm = fmaxf(rm, __shfl_xor(rm, 32, 64));
    if (l == 0) atomicMax(kmx + h, __float_as_uint(rm));   // norm^2, >=0
  } else {
    #pragma unroll
    for (int mt = 0; mt < 4; mt++) {
      #pragma unroll
      for (int nt = 0; nt < 4; nt++) {
        const int d = nt * 16 + l15;
        u16x4 o;
        #pragma unroll
        for (int r = 0; r < 4; r++) o[r] = f2bf(acc[mt][nt][r] + bv4[nt]);
        *reinterpret_cast<u16x4*>(
            vtb + ((size_t)h * 64 + d) * SL + mrow0 + mt * 16 + lg * 4) = o;
      }
    }
  }
}

// ---- Flash attention: 2 waves/WG, wave = KV half x BOTH 32-q groups.
// Wave-PRIVATE dbuf LDS staging (no in-loop barriers, counted vmcnt(8)).
// K tile [32k][64d], V tile fused [32 rows][64 shorts] (d-halves share rows),
// both full-XOR swizzled (0 conflicts). Fixed-bound softmax, -M via MFMA,
// row-sum via MFMA ones-trick.
extern "C" __global__ __launch_bounds__(128) void k_attn(
    const unsigned short* __restrict__ qb, const unsigned short* __restrict__ kbi,
    const unsigned short* __restrict__ vt, const float* __restrict__ qn2,
    const unsigned* __restrict__ kmx, unsigned short* __restrict__ aout) {
  __shared__ alignas(16) unsigned char smem[32768];
  const int t = threadIdx.x, w = t >> 6, l = t & 63;
  const int l31 = l & 31, s = l >> 5;
  const int bid = blockIdx.x;
  const int sid = (bid & 7) * 96 + (bid >> 3);   // XCD head-clustering
  const int h = sid >> 6, qt = sid & 63;
  const unsigned short* qh = qb + (size_t)h * SL * 64;
  const unsigned short* kh = kbi + ((size_t)h * SL + w * 2048) * 64;
  const unsigned short* vh = vt + (size_t)h * 64 * SL + w * 2048;
  const int q0 = qt * 64 + l31;                  // q-group 0
  const int q1 = q0 + 32;                        // q-group 1
  const float kx = __uint_as_float(kmx[h]);
  const float M0 = sqrtf(qn2[(size_t)h * SL + q0] * kx);
  const float M1 = sqrtf(qn2[(size_t)h * SL + q1] * kx);
  s16x8 qf0[4], qf1[4];
  #pragma unroll
  for (int c = 0; c < 4; c++) {
    qf0[c] = *reinterpret_cast<const s16x8*>(qh + (size_t)q0 * 64 + c * 16 + s * 8);
    qf1[c] = *reinterpret_cast<const s16x8*>(qh + (size_t)q1 * 64 + c * 16 + s * 8);
  }
  s16x8 ones;
  #pragma unroll
  for (int e = 0; e < 8; e++) ones[e] = (short)0x3F80;   // bf16 1.0
  s16x8 qm0 = (s16x8)0, qm1 = (s16x8)0;
  if (s == 0) { qm0[0] = (short)f2bf(-M0); qm1[0] = (short)f2bf(-M1); }
  f32x16 o00 = (f32x16)0.f, o01 = (f32x16)0.f;   // qg0: dt0, dt1
  f32x16 o10 = (f32x16)0.f, o11 = (f32x16)0.f;   // qg1
  f32x16 lacc0 = (f32x16)0.f, lacc1 = (f32x16)0.f;
  // staging source offsets (pre-inverse-swizzled; LDS dest linear)
  int koff[4], voff[4];
  #pragma unroll
  for (int c = 0; c < 4; c++) {
    int i = c * 64 + l;
    int row = i >> 3, sb = i & 7;
    int bp = sb ^ ((row ^ (row >> 3)) & 7);
    koff[c] = row * 64 + bp * 8;                        // K: key row, d block
    int d = row + 32 * (bp >> 2);                       // V: fused row -> (d, kblk)
    voff[c] = d * SL + (bp & 3) * 8;
  }
  // fragment read offsets
  const int sr = (l31 ^ (l31 >> 3)) & 7;
  int kfo[4], vfo[4];
  #pragma unroll
  for (int c = 0; c < 4; c++) kfo[c] = (l31 << 6) + (((c * 2 + s) ^ sr) << 3);
  #pragma unroll
  for (int dt = 0; dt < 2; dt++)
    #pragma unroll
    for (int m = 0; m < 2; m++)
      vfo[dt * 2 + m] = (l31 << 6) + (((dt * 4 + m * 2 + s) ^ sr) << 3);
  unsigned short* base = (unsigned short*)smem + w * 8192;
  unsigned short* kb0 = base;
  unsigned short* kb1 = base + 2048;
  unsigned short* vb0 = base + 4096;
  unsigned short* vb1 = base + 6144;

#define STAGE(KB, VB, LB)                                      \
  do {                                                         \
    _Pragma("unroll")                                          \
    for (int c = 0; c < 4; c++) {                              \
      ASYNC16(kh + (size_t)(LB) * 64 + koff[c], (KB) + c * 512); \
      ASYNC16(vh + (LB) + voff[c], (VB) + c * 512);            \
    }                                                          \
  } while (0)

#define LDF(P, O) (*reinterpret_cast<const s16x8*>((P) + (O)))

#define PACKPV(STK, MM, VA, VB, OA, OB, LA)                                         \
  do {                                                                              \
    const int b0 = (MM) * 8;                                                        \
    unsigned w0, w1, w2, w3;                                                        \
    asm("v_cvt_pk_bf16_f32 %0, %1, %2" : "=v"(w0) : "v"(STK[b0 + 0]), "v"(STK[b0 + 1])); \
    asm("v_cvt_pk_bf16_f32 %0, %1, %2" : "=v"(w1) : "v"(STK[b0 + 2]), "v"(STK[b0 + 3])); \
    asm("v_cvt_pk_bf16_f32 %0, %1, %2" : "=v"(w2) : "v"(STK[b0 + 4]), "v"(STK[b0 + 5])); \
    asm("v_cvt_pk_bf16_f32 %0, %1, %2" : "=v"(w3) : "v"(STK[b0 + 6]), "v"(STK[b0 + 7])); \
    asm volatile("v_permlane32_swap_b32 %0, %1" : "+v"(w0), "+v"(w2));              \
    asm volatile("v_permlane32_swap_b32 %0, %1" : "+v"(w1), "+v"(w3));              \
    u32x4 wv_;                                                                      \
    wv_[0] = w0; wv_[1] = w1; wv_[2] = w2; wv_[3] = w3;                             \
    s16x8 pbf = *reinterpret_cast<s16x8*>(&wv_);                                    \
    __builtin_amdgcn_s_setprio(1);                                                  \
    OA = MF32(VA, pbf, OA);                                                         \
    OB = MF32(VB, pbf, OB);                                                         \
    LA = MF32(ones, pbf, LA);                                                       \
    __builtin_amdgcn_s_setprio(0);                                                  \
  } while (0)

#define BODY(KB, VB)                                                         \
  do {                                                                       \
    s16x8 kfr0 = LDF(KB, kfo[0]), kfr1 = LDF(KB, kfo[1]);                    \
    s16x8 kfr2 = LDF(KB, kfo[2]), kfr3 = LDF(KB, kfo[3]);                    \
    s16x8 vf00 = LDF(VB, vfo[0]), vf01 = LDF(VB, vfo[1]);                    \
    s16x8 vf10 = LDF(VB, vfo[2]), vf11 = LDF(VB, vfo[3]);                    \
    f32x16 st0 = (f32x16)0.f, st1 = (f32x16)0.f;                             \
    __builtin_amdgcn_s_setprio(1);                                           \
    st0 = MF32(kfr0, qf0[0], st0); st0 = MF32(kfr1, qf0[1], st0);            \
    st0 = MF32(kfr2, qf0[2], st0); st0 = MF32(kfr3, qf0[3], st0);            \
    st1 = MF32(kfr0, qf1[0], st1); st1 = MF32(kfr1, qf1[1], st1);            \
    st1 = MF32(kfr2, qf1[2], st1); st1 = MF32(kfr3, qf1[3], st1);            \
    st0 = MF32(ones, qm0, st0);                                              \
    st1 = MF32(ones, qm1, st1);                                              \
    __builtin_amdgcn_s_setprio(0);                                           \
    _Pragma("unroll")                                                        \
    for (int r = 0; r < 16; r++) st0[r] = exp2f(st0[r]);                     \
    _Pragma("unroll")                                                        \
    for (int r = 0; r < 16; r++) st1[r] = exp2f(st1[r]);                     \
    PACKPV(st0, 0, vf00, vf10, o00, o01, lacc0);                             \
    PACKPV(st0, 1, vf01, vf11, o00, o01, lacc0);                             \
    PACKPV(st1, 0, vf00, vf10, o10, o11, lacc1);                             \
    PACKPV(st1, 1, vf01, vf11, o10, o11, lacc1);                             \
  } while (0)

  STAGE(kb0, vb0, 0);
  #pragma unroll 1
  for (int lb = 0; lb < 2048; lb += 64) {
    STAGE(kb1, vb1, lb + 32);
    asm volatile("s_waitcnt vmcnt(8)" ::: "memory");
    BODY(kb0, vb0);
    if (lb + 64 < 2048) {
      STAGE(kb0, vb0, lb + 64);
      asm volatile("s_waitcnt vmcnt(8)" ::: "memory");
    } else {
      asm volatile("s_waitcnt vmcnt(0)" ::: "memory");
    }
    BODY(kb1, vb1);
  }
#undef STAGE
#undef BODY
#undef PACKPV
#undef LDF

  // merge the two halves (same M shift => plain adds); overlay staging LDS
  const float ls0 = lacc0[0], ls1 = lacc1[0];
  float* o_m = (float*)smem;                 // [2 qg][32 q][68]
  float* l_m = (float*)(smem + 17408);       // [2 qg][32]
  __syncthreads();
  if (w == 1) {
    #pragma unroll
    for (int rq = 0; rq < 4; rq++) {
      f32x4 v0, v1, v2, v3;
      #pragma unroll
      for (int j = 0; j < 4; j++) {
        v0[j] = o00[rq * 4 + j]; v1[j] = o01[rq * 4 + j];
        v2[j] = o10[rq * 4 + j]; v3[j] = o11[rq * 4 + j];
      }
      *reinterpret_cast<f32x4*>(&o_m[(0 * 32 + l31) * 68 + 0 + rq * 8 + s * 4]) = v0;
      *reinterpret_cast<f32x4*>(&o_m[(0 * 32 + l31) * 68 + 32 + rq * 8 + s * 4]) = v1;
      *reinterpret_cast<f32x4*>(&o_m[(1 * 32 + l31) * 68 + 0 + rq * 8 + s * 4]) = v2;
      *reinterpret_cast<f32x4*>(&o_m[(1 * 32 + l31) * 68 + 32 + rq * 8 + s * 4]) = v3;
    }
    if (s == 0) { l_m[l31] = ls0; l_m[32 + l31] = ls1; }
  }
  __syncthreads();
  if (w == 0) {
    const float linv0 = 1.f / (ls0 + l_m[l31]);
    const float linv1 = 1.f / (ls1 + l_m[32 + l31]);
    #pragma unroll
    for (int rq = 0; rq < 4; rq++) {
      f32x4 b00 = *reinterpret_cast<const f32x4*>(&o_m[(0 * 32 + l31) * 68 + 0 + rq * 8 + s * 4]);
      f32x4 b01 = *reinterpret_cast<const f32x4*>(&o_m[(0 * 32 + l31) * 68 + 32 + rq * 8 + s * 4]);
      f32x4 b10 = *reinterpret_cast<const f32x4*>(&o_m[(1 * 32 + l31) * 68 + 0 + rq * 8 + s * 4]);
      f32x4 b11 = *reinterpret_cast<const f32x4*>(&o_m[(1 * 32 + l31) * 68 + 32 + rq * 8 + s * 4]);
      u16x4 a0, a1, a2, a3;
      #pragma unroll
      for (int j = 0; j < 4; j++) {
        a0[j] = f2bf((o00[rq * 4 + j] + b00[j]) * linv0);
        a1[j] = f2bf((o01[rq * 4 + j] + b01[j]) * linv0);
        a2[j] = f2bf((o10[rq * 4 + j] + b10[j]) * linv1);
        a3[j] = f2bf((o11[rq * 4 + j] + b11[j]) * linv1);
      }
      *reinterpret_cast<u16x4*>(aout + (size_t)q0 * DM + h * 64 + 0 + rq * 8 + s * 4) = a0;
      *reinterpret_cast<u16x4*>(aout + (size_t)q0 * DM + h * 64 + 32 + rq * 8 + s * 4) = a1;
      *reinterpret_cast<u16x4*>(aout + (size_t)q1 * DM + h * 64 + 0 + rq * 8 + s * 4) = a2;
      *reinterpret_cast<u16x4*>(aout + (size_t)q1 * DM + h * 64 + 32 + rq * 8 + s * 4) = a3;
    }
  }
}

// ---- out-proj GEMM + bias + residual -> y (fp32), 128x128 tile, async dbuf ----
extern "C" __global__ __launch_bounds__(256) void k_out(
    const unsigned short* __restrict__ abf, const unsigned short* __restrict__ wot,
    const float* __restrict__ bias, const float* __restrict__ x, float* __restrict__ y) {
  __shared__ alignas(16) unsigned short a_lds[2][8192];
  __shared__ alignas(16) unsigned short b_lds[2][8192];
  const int t = threadIdx.x, w = t >> 6, l = t & 63;
  const int l15 = l & 15, lg = l >> 4;
  const int wr = w >> 1, wc = w & 1;
  const int n0 = blockIdx.x * 128, m0 = blockIdx.y * 128;
  f32x4 acc[4][4];
  #pragma unroll
  for (int mt = 0; mt < 4; mt++)
    #pragma unroll
    for (int nt = 0; nt < 4; nt++) acc[mt][nt] = (f32x4)0.f;
  int soff[4];
  #pragma unroll
  for (int c = 0; c < 4; c++) {
    int i = c * 256 + t;
    int row = i >> 3, bp = i & 7;
    soff[c] = row * DM + (bp ^ (row & 7)) * 8;
  }
  const unsigned short* asrc = abf + (size_t)m0 * DM;
  const unsigned short* bsrc = wot + (size_t)n0 * DM;

#define STAGE128(B, KK)                                                   \
  do {                                                                    \
    _Pragma("unroll")                                                     \
    for (int c = 0; c < 4; c++) {                                         \
      ASYNC16(asrc + (KK) + soff[c], &a_lds[B][0] + c * 2048 + w * 512);  \
      ASYNC16(bsrc + (KK) + soff[c], &b_lds[B][0] + c * 2048 + w * 512);  \
    }                                                                     \
  } while (0)

#define GEMM128(B)                                                            \
  do {                                                                        \
    _Pragma("unroll")                                                         \
    for (int kc = 0; kc < 2; kc++) {                                          \
      s16x8 af[4], bfv[4];                                                    \
      _Pragma("unroll")                                                       \
      for (int mt = 0; mt < 4; mt++)                                          \
        af[mt] = *reinterpret_cast<const s16x8*>(                             \
            &a_lds[B][swz(wr * 64 + mt * 16 + l15, kc * 32 + lg * 8)]);       \
      _Pragma("unroll")                                                       \
      for (int nt = 0; nt < 4; nt++)                                          \
        bfv[nt] = *reinterpret_cast<const s16x8*>(                            \
            &b_lds[B][swz(wc * 64 + nt * 16 + l15, kc * 32 + lg * 8)]);       \
      _Pragma("unroll")                                                       \
      for (int mt = 0; mt < 4; mt++)                                          \
        _Pragma("unroll")                                                     \
        for (int nt = 0; nt < 4; nt++)                                        \
          acc[mt][nt] = __builtin_amdgcn_mfma_f32_16x16x32_bf16(              \
              af[mt], bfv[nt], acc[mt][nt], 0, 0, 0);                         \
    }                                                                         \
  } while (0)

  STAGE128(0, 0);
  WAITB();
  #pragma unroll 1
  for (int kk = 0; kk < DM; kk += 128) {
    STAGE128(1, kk + 64);
    GEMM128(0);
    WAITB();
    if (kk + 128 < DM) STAGE128(0, kk + 128);
    GEMM128(1);
    WAITB();
  }
#undef STAGE128
#undef GEMM128

  const int mrow0 = m0 + wr * 64;
  #pragma unroll
  for (int nt = 0; nt < 4; nt++) {
    const int n = n0 + wc * 64 + nt * 16 + l15;
    const float bv = bias[n];
    #pragma unroll
    for (int mt = 0; mt < 4; mt++) {
      #pragma unroll
      for (int r = 0; r < 4; r++) {
        const int m = mrow0 + mt * 16 + lg * 4 + r;
        y[(size_t)m * DM + n] = acc[mt][nt][r] + bv + x[(size_t)m * DM + n];
      }
    }
  }
}

extern "C" __global__ __launch_bounds__(256) void k_ln(
    const float* __restrict__ y, const float* __restrict__ g, const float* __restrict__ b,
    float* __restrict__ out) {
  const int row = blockIdx.x, t = threadIdx.x;
  const float* yr = y + (size_t)row * DM;
  float v0 = yr[t], v1 = yr[t + 256], v2 = yr[t + 512];
  float sum = v0 + v1 + v2;
  float sq = v0 * v0 + v1 * v1 + v2 * v2;
  #pragma unroll
  for (int off = 1; off < 64; off <<= 1) {
    sum += __shfl_xor(sum, off, 64);
    sq += __shfl_xor(sq, off, 64);
  }
  __shared__ float ls[8];
  const int wv = t >> 6, l = t & 63;
  if (l == 0) { ls[wv] = sum; ls[4 + wv] = sq; }
  __syncthreads();
  sum = ls[0] + ls[1] + ls[2] + ls[3];
  sq = ls[4] + ls[5] + ls[6] + ls[7];
  const float mu = sum * (1.f / DM);
  const float rstd = rsqrtf(sq * (1.f / DM) - mu * mu + 1e-5f);
  out[(size_t)row * DM + t] = (v0 - mu) * rstd * g[t] + b[t];
  out[(size_t)row * DM + t + 256] = (v1 - mu) * rstd * g[t + 256] + b[t + 256];
  out[(size_t)row * DM + t + 512] = (v2 - mu) * rstd * g[t + 512] + b[t + 512];
}

extern "C" void kernel_launch(void* const* d_in, const int* in_sizes, int n_in,
                              void* d_out, int out_size, void* d_ws, size_t ws_size,
                              hipStream_t stream) {
  (void)in_sizes; (void)n_in; (void)out_size; (void)ws_size;
  const float* x = (const float*)d_in[0];
  const float* Wa = (const float*)d_in[1];
  const float* ba = (const float*)d_in[2];
  const float* Wo = (const float*)d_in[3];
  const float* bo = (const float*)d_in[4];
  const float* lng = (const float*)d_in[5];
  const float* lnb = (const float*)d_in[6];
  float* out = (float*)d_out;

  unsigned short* ws16 = (unsigned short*)d_ws;
  unsigned short* xbf = ws16;                 // 4096x768
  unsigned short* wat = xbf + 3145728;        // 2304x768 (W_attn^T)
  unsigned short* wot = wat + 1769472;        // 768x768  (W_out^T)
  unsigned short* qbf = wot + 589824;         // [12][4096][64]
  unsigned short* kbf = qbf + 3145728;        // [12][4096][64]
  unsigned short* vtb = kbf + 3145728;        // [12][64][4096]
  unsigned short* aob = vtb + 3145728;        // 4096x768 attn out
  float* ybuf = (float*)(aob + 3145728);      // 4096x768 fp32
  float* qn2 = ybuf + 3145728;                // [12][4096] |q|^2
  unsigned* kmx = (unsigned*)(qn2 + 49152);   // [12] max |k|^2 (as uint)

  k_prep<<<3648, 256, 0, stream>>>(x, Wa, Wo, xbf, wat, wot, kmx);
  k_qkv<<<dim3(18, 32), 256, 0, stream>>>(xbf, wat, ba, qbf, kbf, vtb, qn2, kmx);
  k_attn<<<768, 128, 0, stream>>>(qbf, kbf, vtb, qn2, kmx, aob);
  k_out<<<dim3(6, 32), 256, 0, stream>>>(aob, wot, bo, x, ybuf);
  k_ln<<<4096, 256, 0, stream>>>(ybuf, lng, lnb, out);
}

// Round 10
// 168.542 us; speedup vs baseline: 1.5016x; 1.3081x over previous
//
#include <hip/hip_runtime.h>
#include <cstdint>
#include <cstddef>

#define SL 4096
#define DM 768

typedef short s16x8 __attribute__((ext_vector_type(8)));
typedef unsigned short u16x8 __attribute__((ext_vector_type(8)));
typedef unsigned short u16x4 __attribute__((ext_vector_type(4)));
typedef float f32x4 __attribute__((ext_vector_type(4)));
typedef float f32x16 __attribute__((ext_vector_type(16)));
typedef unsigned int u32x4 __attribute__((ext_vector_type(4)));

__device__ __forceinline__ unsigned short f2bf(float f) {
  unsigned u = __float_as_uint(f);
  u = u + 0x7fffu + ((u >> 16) & 1u);   // round-to-nearest-even
  return (unsigned short)(u >> 16);
}

// 16B-block XOR swizzle within a 64-short (128B) row (guide G4/T2).
__device__ __forceinline__ int swz(int row, int col) {
  return (row << 6) + ((((col >> 3) ^ row) & 7) << 3) + (col & 7);
}

#define ASYNC16(G, L)                                                        \
  __builtin_amdgcn_global_load_lds(                                          \
      (const __attribute__((address_space(1))) void*)(G),                    \
      (__attribute__((address_space(3))) void*)(L), 16, 0, 0)

#define WAITB()                                   \
  do {                                            \
    asm volatile("s_waitcnt vmcnt(0)" ::: "memory"); \
    __builtin_amdgcn_s_barrier();                 \
  } while (0)

#define MF32(A, B, C) __builtin_amdgcn_mfma_f32_32x32x16_bf16((A), (B), (C), 0, 0, 0)

// ---- fused prep: x->bf16 cvt, W_attn^T, W_out^T, kmx zero ----
__device__ __forceinline__ void tr_body(
    const float* __restrict__ in, unsigned short* __restrict__ out,
    int R, int C, int bx, int by, float (*tile)[65], int t) {
  const int r0 = by * 64, c0 = bx * 64;
  const int lr = t >> 2, lcb = (t & 3) * 16;
  #pragma unroll
  for (int j = 0; j < 16; j += 4) {
    f32x4 v = *reinterpret_cast<const f32x4*>(in + (size_t)(r0 + lr) * C + c0 + lcb + j);
    tile[lr][lcb + j + 0] = v[0];
    tile[lr][lcb + j + 1] = v[1];
    tile[lr][lcb + j + 2] = v[2];
    tile[lr][lcb + j + 3] = v[3];
  }
  __syncthreads();
  #pragma unroll
  for (int j = 0; j < 16; j += 4) {
    u16x4 o;
    o[0] = f2bf(tile[lcb + j + 0][lr]);
    o[1] = f2bf(tile[lcb + j + 1][lr]);
    o[2] = f2bf(tile[lcb + j + 2][lr]);
    o[3] = f2bf(tile[lcb + j + 3][lr]);
    *reinterpret_cast<u16x4*>(out + (size_t)(c0 + lr) * R + r0 + lcb + j) = o;
  }
}

extern "C" __global__ __launch_bounds__(256) void k_prep(
    const float* __restrict__ x, const float* __restrict__ Wa,
    const float* __restrict__ Wo, unsigned short* __restrict__ xbf,
    unsigned short* __restrict__ wat, unsigned short* __restrict__ wot,
    unsigned* __restrict__ kmx) {
  __shared__ float tile[64][65];
  const int b = blockIdx.x, t = threadIdx.x;
  if (b < 3072) {
    if (b == 0 && t < 12) kmx[t] = 0u;
    const int i = (b * 256 + t) * 4;
    f32x4 v = *reinterpret_cast<const f32x4*>(x + i);
    u16x4 o;
    o[0] = f2bf(v[0]); o[1] = f2bf(v[1]); o[2] = f2bf(v[2]); o[3] = f2bf(v[3]);
    *reinterpret_cast<u16x4*>(xbf + i) = o;
  } else if (b < 3504) {
    const int bb = b - 3072;
    tr_body(Wa, wat, 768, 2304, bb % 36, bb / 36, tile, t);
  } else {
    const int bb = b - 3504;
    tr_body(Wo, wot, 768, 768, bb % 12, bb / 12, tile, t);
  }
}

// ---- QKV GEMM, 128x128 tile, BK=64, async dbuf; epilogue computes row norms ----
extern "C" __global__ __launch_bounds__(256) void k_qkv(
    const unsigned short* __restrict__ xbf, const unsigned short* __restrict__ wt,
    const float* __restrict__ bias, unsigned short* __restrict__ qb,
    unsigned short* __restrict__ kbo, unsigned short* __restrict__ vtb,
    float* __restrict__ qn2, unsigned* __restrict__ kmx) {
  __shared__ alignas(16) unsigned short a_lds[2][8192];
  __shared__ alignas(16) unsigned short b_lds[2][8192];
  const int t = threadIdx.x, w = t >> 6, l = t & 63;
  const int l15 = l & 15, lg = l >> 4;
  const int wr = w >> 1, wc = w & 1;
  const int n0 = blockIdx.x * 128, m0 = blockIdx.y * 128;
  f32x4 acc[4][4];
  #pragma unroll
  for (int mt = 0; mt < 4; mt++)
    #pragma unroll
    for (int nt = 0; nt < 4; nt++) acc[mt][nt] = (f32x4)0.f;
  int soff[4];
  #pragma unroll
  for (int c = 0; c < 4; c++) {
    int i = c * 256 + t;
    int row = i >> 3, bp = i & 7;
    soff[c] = row * DM + (bp ^ (row & 7)) * 8;
  }
  const unsigned short* asrc = xbf + (size_t)m0 * DM;
  const unsigned short* bsrc = wt + (size_t)n0 * DM;

#define STAGE128(B, KK)                                                   \
  do {                                                                    \
    _Pragma("unroll")                                                     \
    for (int c = 0; c < 4; c++) {                                         \
      ASYNC16(asrc + (KK) + soff[c], &a_lds[B][0] + c * 2048 + w * 512);  \
      ASYNC16(bsrc + (KK) + soff[c], &b_lds[B][0] + c * 2048 + w * 512);  \
    }                                                                     \
  } while (0)

#define GEMM128(B)                                                            \
  do {                                                                        \
    _Pragma("unroll")                                                         \
    for (int kc = 0; kc < 2; kc++) {                                          \
      s16x8 af[4], bfv[4];                                                    \
      _Pragma("unroll")                                                       \
      for (int mt = 0; mt < 4; mt++)                                          \
        af[mt] = *reinterpret_cast<const s16x8*>(                             \
            &a_lds[B][swz(wr * 64 + mt * 16 + l15, kc * 32 + lg * 8)]);       \
      _Pragma("unroll")                                                       \
      for (int nt = 0; nt < 4; nt++)                                          \
        bfv[nt] = *reinterpret_cast<const s16x8*>(                            \
            &b_lds[B][swz(wc * 64 + nt * 16 + l15, kc * 32 + lg * 8)]);       \
      _Pragma("unroll")                                                       \
      for (int mt = 0; mt < 4; mt++)                                          \
        _Pragma("unroll")                                                     \
        for (int nt = 0; nt < 4; nt++)                                        \
          acc[mt][nt] = __builtin_amdgcn_mfma_f32_16x16x32_bf16(              \
              af[mt], bfv[nt], acc[mt][nt], 0, 0, 0);                         \
    }                                                                         \
  } while (0)

  STAGE128(0, 0);
  WAITB();
  #pragma unroll 1
  for (int kk = 0; kk < DM; kk += 128) {
    STAGE128(1, kk + 64);
    GEMM128(0);
    WAITB();
    if (kk + 128 < DM) STAGE128(0, kk + 128);
    GEMM128(1);
    WAITB();
  }
#undef STAGE128
#undef GEMM128

  const int secn = (n0 >= 1536) ? 2 : (n0 >= 768 ? 1 : 0);
  const int nbase = n0 - secn * 768 + wc * 64;   // 64-aligned within section
  const int h = nbase >> 6;                      // this wave's head
  const int mrow0 = m0 + wr * 64;
  float bv4[4];
  #pragma unroll
  for (int nt = 0; nt < 4; nt++) bv4[nt] = bias[secn * 768 + nbase + nt * 16 + l15];

  if (secn == 0) {
    const float QS = 0.180336880f;               // 0.125*log2(e)
    float s2[4][4];
    #pragma unroll
    for (int mt = 0; mt < 4; mt++) {
      #pragma unroll
      for (int r = 0; r < 4; r++) s2[mt][r] = 0.f;
    }
    #pragma unroll
    for (int mt = 0; mt < 4; mt++) {
      #pragma unroll
      for (int nt = 0; nt < 4; nt++) {
        const int d = nt * 16 + l15;
        #pragma unroll
        for (int r = 0; r < 4; r++) {
          const int m = mrow0 + mt * 16 + lg * 4 + r;
          float v = (acc[mt][nt][r] + bv4[nt]) * QS;
          qb[((size_t)h * SL + m) * 64 + d] = f2bf(v);
          s2[mt][r] = fmaf(v, v, s2[mt][r]);
        }
      }
    }
    #pragma unroll
    for (int mt = 0; mt < 4; mt++)
      #pragma unroll
      for (int r = 0; r < 4; r++) {
        #pragma unroll
        for (int off = 1; off < 16; off <<= 1)
          s2[mt][r] += __shfl_xor(s2[mt][r], off, 64);
      }
    if (l15 == 0) {
      #pragma unroll
      for (int mt = 0; mt < 4; mt++)
        #pragma unroll
        for (int r = 0; r < 4; r++)
          qn2[(size_t)h * SL + mrow0 + mt * 16 + lg * 4 + r] = s2[mt][r];
    }
  } else if (secn == 1) {
    float s2[4][4];
    #pragma unroll
    for (int mt = 0; mt < 4; mt++) {
      #pragma unroll
      for (int r = 0; r < 4; r++) s2[mt][r] = 0.f;
    }
    #pragma unroll
    for (int mt = 0; mt < 4; mt++) {
      #pragma unroll
      for (int nt = 0; nt < 4; nt++) {
        const int d = nt * 16 + l15;
        #pragma unroll
        for (int r = 0; r < 4; r++) {
          const int m = mrow0 + mt * 16 + lg * 4 + r;
          float v = acc[mt][nt][r] + bv4[nt];
          kbo[((size_t)h * SL + m) * 64 + d] = f2bf(v);
          s2[mt][r] = fmaf(v, v, s2[mt][r]);
        }
      }
    }
    float rm = 0.f;
    #pragma unroll
    for (int mt = 0; mt < 4; mt++)
      #pragma unroll
      for (int r = 0; r < 4; r++) {
        #pragma unroll
        for (int off = 1; off < 16; off <<= 1)
          s2[mt][r] += __shfl_xor(s2[mt][r], off, 64);
        rm = fmaxf(rm, s2[mt][r]);
      }
    rm = fmaxf(rm, __shfl_xor(rm, 16, 64));
    rm = fmaxf(rm, __shfl_xor(rm, 32, 64));
    if (l == 0) atomicMax(kmx + h, __float_as_uint(rm));   // norm^2, >=0
  } else {
    #pragma unroll
    for (int mt = 0; mt < 4; mt++) {
      #pragma unroll
      for (int nt = 0; nt < 4; nt++) {
        const int d = nt * 16 + l15;
        u16x4 o;
        #pragma unroll
        for (int r = 0; r < 4; r++) o[r] = f2bf(acc[mt][nt][r] + bv4[nt]);
        *reinterpret_cast<u16x4*>(
            vtb + ((size_t)h * 64 + d) * SL + mrow0 + mt * 16 + lg * 4) = o;
      }
    }
  }
}

// 32x32 swapped attention body, KVBLK=32, fixed-bound softmax (-M via MFMA),
// row-sum via MFMA ones-trick. kfo/vfo are precomputed conflict-free offsets.
__device__ __forceinline__ void attn_body32f(
    const unsigned short* kb, const unsigned short* vb,
    const s16x8* qf, f32x16* ot, f32x16& lacc, s16x8 qm,
    const int* kfo, const int* vfo, s16x8 ones) {
  f32x16 st = (f32x16)0.f;
  __builtin_amdgcn_s_setprio(1);
  #pragma unroll
  for (int c = 0; c < 4; c++) {
    s16x8 kf = *reinterpret_cast<const s16x8*>(&kb[kfo[c]]);
    st = MF32(kf, qf[c], st);
  }
  st = MF32(ones, qm, st);
  __builtin_amdgcn_s_setprio(0);
  #pragma unroll
  for (int r = 0; r < 16; r++) st[r] = exp2f(st[r]);
  #pragma unroll
  for (int m = 0; m < 2; m++) {
    const int m0 = m * 8;
    unsigned w0, w1, w2, w3;
    asm("v_cvt_pk_bf16_f32 %0, %1, %2" : "=v"(w0) : "v"(st[m0 + 0]), "v"(st[m0 + 1]));
    asm("v_cvt_pk_bf16_f32 %0, %1, %2" : "=v"(w1) : "v"(st[m0 + 2]), "v"(st[m0 + 3]));
    asm("v_cvt_pk_bf16_f32 %0, %1, %2" : "=v"(w2) : "v"(st[m0 + 4]), "v"(st[m0 + 5]));
    asm("v_cvt_pk_bf16_f32 %0, %1, %2" : "=v"(w3) : "v"(st[m0 + 6]), "v"(st[m0 + 7]));
    asm volatile("v_permlane32_swap_b32 %0, %1" : "+v"(w0), "+v"(w2));
    asm volatile("v_permlane32_swap_b32 %0, %1" : "+v"(w1), "+v"(w3));
    u32x4 wv_;
    wv_[0] = w0; wv_[1] = w1; wv_[2] = w2; wv_[3] = w3;
    s16x8 pbf = *reinterpret_cast<s16x8*>(&wv_);
    __builtin_amdgcn_s_setprio(1);
    #pragma unroll
    for (int dt = 0; dt < 2; dt++) {
      s16x8 vf = *reinterpret_cast<const s16x8*>(&vb[vfo[m * 2 + dt]]);
      ot[dt] = MF32(vf, pbf, ot[dt]);
    }
    lacc = MF32(ones, pbf, lacc);
    __builtin_amdgcn_s_setprio(0);
  }
}

// Flash attention: 4 waves = 2 q-subtiles x 2 KV-halves; KVBLK=32; async dbuf
// with COUNTED vmcnt(4) (next tile's loads stay in flight across the barrier);
// conflict-free fused V tile [32 rows = d-pair][64 shorts], full-XOR (R9-verified
// 0 conflicts); fixed-bound softmax; LDS merge overlays dead staging buffers.
extern "C" __global__ __launch_bounds__(256) void k_attn(
    const unsigned short* __restrict__ qb, const unsigned short* __restrict__ kbi,
    const unsigned short* __restrict__ vt, const float* __restrict__ qn2,
    const unsigned* __restrict__ kmx, unsigned short* __restrict__ aout) {
  __shared__ alignas(16) unsigned char smem[32768];
  unsigned short* kst = (unsigned short*)smem;             // [4][2048] K staging
  unsigned short* vst = (unsigned short*)(smem + 16384);   // [4][2048] V staging
  const int t = threadIdx.x, w = t >> 6, l = t & 63;
  const int l31 = l & 31, s = l >> 5;
  const int half = w >> 1, qs = w & 1;
  const int bid = blockIdx.x;
  const int sid = (bid & 7) * 96 + (bid >> 3);   // XCD head-clustering
  const int h = sid >> 6, qt = sid & 63;
  const unsigned short* qh = qb + (size_t)h * SL * 64;
  const unsigned short* kh = kbi + ((size_t)h * SL + half * 2048) * 64;
  const unsigned short* vh = vt + (size_t)h * 64 * SL + half * 2048;
  const int q = qt * 64 + qs * 32 + l31;
  const float M = sqrtf(qn2[(size_t)h * SL + q] * __uint_as_float(kmx[h]));
  s16x8 qf[4];
  #pragma unroll
  for (int c = 0; c < 4; c++)
    qf[c] = *reinterpret_cast<const s16x8*>(qh + (size_t)q * 64 + c * 16 + s * 8);
  s16x8 ones;
  #pragma unroll
  for (int e = 0; e < 8; e++) ones[e] = (short)0x3F80;     // bf16 1.0
  s16x8 qm = (s16x8)0;
  if (s == 0) qm[0] = (short)f2bf(-M);                      // k-slot 0 holds -M(q)
  f32x16 ot[2];
  ot[0] = (f32x16)0.f;
  ot[1] = (f32x16)0.f;
  f32x16 lacc = (f32x16)0.f;
  // staging source offsets (pre-inverse-swizzled; LDS dest linear).
  // K tile: [32 keys][64 d], full XOR. V tile fused: row r = d-pair (r, r+32),
  // blocks 0-3 = d=r keys 0..31, blocks 4-7 = d=r+32 keys 0..31, full XOR.
  int koff[2], voff[2];
  #pragma unroll
  for (int c = 0; c < 2; c++) {
    int i = (qs * 2 + c) * 64 + l;
    int row = i >> 3, sb = i & 7;
    int bp = sb ^ ((row ^ (row >> 3)) & 7);
    koff[c] = row * 64 + bp * 8;
    int d = row + 32 * (bp >> 2);
    voff[c] = d * SL + (bp & 3) * 8;
  }
  // fragment read offsets (conflict-free, R9-verified)
  const int sr = (l31 ^ (l31 >> 3)) & 7;
  int kfo[4], vfo[4];
  #pragma unroll
  for (int c = 0; c < 4; c++) kfo[c] = (l31 << 6) + (((c * 2 + s) ^ sr) << 3);
  #pragma unroll
  for (int m = 0; m < 2; m++)
    #pragma unroll
    for (int dt = 0; dt < 2; dt++)
      vfo[m * 2 + dt] = (l31 << 6) + (((dt * 4 + m * 2 + s) ^ sr) << 3);

#define STAGE_KV(B, LB)                                                     \
  do {                                                                      \
    _Pragma("unroll")                                                       \
    for (int c = 0; c < 2; c++) {                                           \
      ASYNC16(kh + (size_t)(LB) * 64 + koff[c],                             \
              kst + (half * 2 + (B)) * 2048 + (qs * 2 + c) * 512);          \
      ASYNC16(vh + (LB) + voff[c],                                          \
              vst + (half * 2 + (B)) * 2048 + (qs * 2 + c) * 512);          \
    }                                                                       \
  } while (0)

  STAGE_KV(0, 0);
  #pragma unroll 1
  for (int lb = 0; lb < 2048; lb += 64) {
    STAGE_KV(1, lb + 32);
    asm volatile("s_waitcnt vmcnt(4)" ::: "memory");   // buf0's 4 done; buf1 in flight
    __builtin_amdgcn_s_barrier();
    attn_body32f(kst + (half * 2) * 2048, vst + (half * 2) * 2048,
                 qf, ot, lacc, qm, kfo, vfo, ones);
    if (lb + 64 < 2048) {
      STAGE_KV(0, lb + 64);
      asm volatile("s_waitcnt vmcnt(4)" ::: "memory"); // buf1's 4 done; buf0 in flight
    } else {
      asm volatile("s_waitcnt vmcnt(0)" ::: "memory"); // tail drain
    }
    __builtin_amdgcn_s_barrier();
    attn_body32f(kst + (half * 2 + 1) * 2048, vst + (half * 2 + 1) * 2048,
                 qf, ot, lacc, qm, kfo, vfo, ones);
  }
#undef STAGE_KV
  // merge the two halves (same M shift => plain adds); overlay staging LDS
  const float lsum = lacc[0];
  float* o_m = (float*)smem;                 // [2][32][68]
  float* l_m = (float*)(smem + 17408);       // [2][32]
  __syncthreads();
  if (half == 1) {
    #pragma unroll
    for (int dt = 0; dt < 2; dt++) {
      #pragma unroll
      for (int rq = 0; rq < 4; rq++) {
        f32x4 v;
        #pragma unroll
        for (int j = 0; j < 4; j++) v[j] = ot[dt][rq * 4 + j];
        *reinterpret_cast<f32x4*>(&o_m[(qs * 32 + l31) * 68 + dt * 32 + rq * 8 + s * 4]) = v;
      }
    }
    if (s == 0) l_m[qs * 32 + l31] = lsum;
  }
  __syncthreads();
  if (half == 0) {
    const float linv = 1.f / (lsum + l_m[qs * 32 + l31]);
    #pragma unroll
    for (int dt = 0; dt < 2; dt++) {
      #pragma unroll
      for (int rq = 0; rq < 4; rq++) {
        f32x4 vb_ = *reinterpret_cast<const f32x4*>(&o_m[(qs * 32 + l31) * 68 + dt * 32 + rq * 8 + s * 4]);
        u16x4 o;
        #pragma unroll
        for (int j = 0; j < 4; j++)
          o[j] = f2bf((ot[dt][rq * 4 + j] + vb_[j]) * linv);
        *reinterpret_cast<u16x4*>(aout + (size_t)q * DM + h * 64 + dt * 32 + rq * 8 + s * 4) = o;
      }
    }
  }
}

// ---- out-proj GEMM + bias + residual -> y (fp32), 128x128 tile, async dbuf ----
extern "C" __global__ __launch_bounds__(256) void k_out(
    const unsigned short* __restrict__ abf, const unsigned short* __restrict__ wot,
    const float* __restrict__ bias, const float* __restrict__ x, float* __restrict__ y) {
  __shared__ alignas(16) unsigned short a_lds[2][8192];
  __shared__ alignas(16) unsigned short b_lds[2][8192];
  const int t = threadIdx.x, w = t >> 6, l = t & 63;
  const int l15 = l & 15, lg = l >> 4;
  const int wr = w >> 1, wc = w & 1;
  const int n0 = blockIdx.x * 128, m0 = blockIdx.y * 128;
  f32x4 acc[4][4];
  #pragma unroll
  for (int mt = 0; mt < 4; mt++)
    #pragma unroll
    for (int nt = 0; nt < 4; nt++) acc[mt][nt] = (f32x4)0.f;
  int soff[4];
  #pragma unroll
  for (int c = 0; c < 4; c++) {
    int i = c * 256 + t;
    int row = i >> 3, bp = i & 7;
    soff[c] = row * DM + (bp ^ (row & 7)) * 8;
  }
  const unsigned short* asrc = abf + (size_t)m0 * DM;
  const unsigned short* bsrc = wot + (size_t)n0 * DM;

#define STAGE128(B, KK)                                                   \
  do {                                                                    \
    _Pragma("unroll")                                                     \
    for (int c = 0; c < 4; c++) {                                         \
      ASYNC16(asrc + (KK) + soff[c], &a_lds[B][0] + c * 2048 + w * 512);  \
      ASYNC16(bsrc + (KK) + soff[c], &b_lds[B][0] + c * 2048 + w * 512);  \
    }                                                                     \
  } while (0)

#define GEMM128(B)                                                            \
  do {                                                                        \
    _Pragma("unroll")                                                         \
    for (int kc = 0; kc < 2; kc++) {                                          \
      s16x8 af[4], bfv[4];                                                    \
      _Pragma("unroll")                                                       \
      for (int mt = 0; mt < 4; mt++)                                          \
        af[mt] = *reinterpret_cast<const s16x8*>(                             \
            &a_lds[B][swz(wr * 64 + mt * 16 + l15, kc * 32 + lg * 8)]);       \
      _Pragma("unroll")                                                       \
      for (int nt = 0; nt < 4; nt++)                                          \
        bfv[nt] = *reinterpret_cast<const s16x8*>(                            \
            &b_lds[B][swz(wc * 64 + nt * 16 + l15, kc * 32 + lg * 8)]);       \
      _Pragma("unroll")                                                       \
      for (int mt = 0; mt < 4; mt++)                                          \
        _Pragma("unroll")                                                     \
        for (int nt = 0; nt < 4; nt++)                                        \
          acc[mt][nt] = __builtin_amdgcn_mfma_f32_16x16x32_bf16(              \
              af[mt], bfv[nt], acc[mt][nt], 0, 0, 0);                         \
    }                                                                         \
  } while (0)

  STAGE128(0, 0);
  WAITB();
  #pragma unroll 1
  for (int kk = 0; kk < DM; kk += 128) {
    STAGE128(1, kk + 64);
    GEMM128(0);
    WAITB();
    if (kk + 128 < DM) STAGE128(0, kk + 128);
    GEMM128(1);
    WAITB();
  }
#undef STAGE128
#undef GEMM128

  const int mrow0 = m0 + wr * 64;
  #pragma unroll
  for (int nt = 0; nt < 4; nt++) {
    const int n = n0 + wc * 64 + nt * 16 + l15;
    const float bv = bias[n];
    #pragma unroll
    for (int mt = 0; mt < 4; mt++) {
      #pragma unroll
      for (int r = 0; r < 4; r++) {
        const int m = mrow0 + mt * 16 + lg * 4 + r;
        y[(size_t)m * DM + n] = acc[mt][nt][r] + bv + x[(size_t)m * DM + n];
      }
    }
  }
}

extern "C" __global__ __launch_bounds__(256) void k_ln(
    const float* __restrict__ y, const float* __restrict__ g, const float* __restrict__ b,
    float* __restrict__ out) {
  const int row = blockIdx.x, t = threadIdx.x;
  const float* yr = y + (size_t)row * DM;
  float v0 = yr[t], v1 = yr[t + 256], v2 = yr[t + 512];
  float sum = v0 + v1 + v2;
  float sq = v0 * v0 + v1 * v1 + v2 * v2;
  #pragma unroll
  for (int off = 1; off < 64; off <<= 1) {
    sum += __shfl_xor(sum, off, 64);
    sq += __shfl_xor(sq, off, 64);
  }
  __shared__ float ls[8];
  const int wv = t >> 6, l = t & 63;
  if (l == 0) { ls[wv] = sum; ls[4 + wv] = sq; }
  __syncthreads();
  sum = ls[0] + ls[1] + ls[2] + ls[3];
  sq = ls[4] + ls[5] + ls[6] + ls[7];
  const float mu = sum * (1.f / DM);
  const float rstd = rsqrtf(sq * (1.f / DM) - mu * mu + 1e-5f);
  out[(size_t)row * DM + t] = (v0 - mu) * rstd * g[t] + b[t];
  out[(size_t)row * DM + t + 256] = (v1 - mu) * rstd * g[t + 256] + b[t + 256];
  out[(size_t)row * DM + t + 512] = (v2 - mu) * rstd * g[t + 512] + b[t + 512];
}

extern "C" void kernel_launch(void* const* d_in, const int* in_sizes, int n_in,
                              void* d_out, int out_size, void* d_ws, size_t ws_size,
                              hipStream_t stream) {
  (void)in_sizes; (void)n_in; (void)out_size; (void)ws_size;
  const float* x = (const float*)d_in[0];
  const float* Wa = (const float*)d_in[1];
  const float* ba = (const float*)d_in[2];
  const float* Wo = (const float*)d_in[3];
  const float* bo = (const float*)d_in[4];
  const float* lng = (const float*)d_in[5];
  const float* lnb = (const float*)d_in[6];
  float* out = (float*)d_out;

  unsigned short* ws16 = (unsigned short*)d_ws;
  unsigned short* xbf = ws16;                 // 4096x768
  unsigned short* wat = xbf + 3145728;        // 2304x768 (W_attn^T)
  unsigned short* wot = wat + 1769472;        // 768x768  (W_out^T)
  unsigned short* qbf = wot + 589824;         // [12][4096][64]
  unsigned short* kbf = qbf + 3145728;        // [12][4096][64]
  unsigned short* vtb = kbf + 3145728;        // [12][64][4096]
  unsigned short* aob = vtb + 3145728;        // 4096x768 attn out
  float* ybuf = (float*)(aob + 3145728);      // 4096x768 fp32
  float* qn2 = ybuf + 3145728;                // [12][4096] |q|^2
  unsigned* kmx = (unsigned*)(qn2 + 49152);   // [12] max |k|^2 (as uint)

  k_prep<<<3648, 256, 0, stream>>>(x, Wa, Wo, xbf, wat, wot, kmx);
  k_qkv<<<dim3(18, 32), 256, 0, stream>>>(xbf, wat, ba, qbf, kbf, vtb, qn2, kmx);
  k_attn<<<768, 256, 0, stream>>>(qbf, kbf, vtb, qn2, kmx, aob);
  k_out<<<dim3(6, 32), 256, 0, stream>>>(aob, wot, bo, x, ybuf);
  k_ln<<<4096, 256, 0, stream>>>(ybuf, lng, lnb, out);
}